// Round 10
// baseline (1851.266 us; speedup 1.0000x reference)
//
#include <hip/hip_runtime.h>
#include <math.h>

// Problem constants
#define Bz 4
#define Tz 1024
#define Kz 128
#define Hz 8
#define Dz 4
#define KSz 5
#define EPSz 1e-5f
#define SCALEf 0.2973017787506803f   // 128^-0.25

// ---------------------------------------------------------------------------
// x = x + pos_table (broadcast over batch); writes to workspace copy
__global__ __launch_bounds__(256) void k_add_pos(const float* __restrict__ x,
                                                 const float* __restrict__ pos,
                                                 float* __restrict__ xb) {
    int i = blockIdx.x * 256 + threadIdx.x;      // float4 index
    const int n4 = Bz * Tz * Kz / 4;
    if (i >= n4) return;
    float4 xv = reinterpret_cast<const float4*>(x)[i];
    int tk = i % (Tz * Kz / 4);
    float4 pv = reinterpret_cast<const float4*>(pos)[tk];
    xv.x += pv.x; xv.y += pv.y; xv.z += pv.z; xv.w += pv.w;
    reinterpret_cast<float4*>(xb)[i] = xv;
}

// ---------------------------------------------------------------------------
// Coalesced conv weight transpose: (D, 1024, 128, 5) -> (D, 5, 128, 1024)
// Block tile: 64 oc x (16 ic x 5 s). LDS stride 81 -> max 2-way alias = free.
// grid (16, 8, D), block 256.
__global__ __launch_bounds__(256) void k_tp_conv_t(const float* __restrict__ w,
                                                   float* __restrict__ wt) {
    const int oc0 = blockIdx.x << 6;
    const int ic0 = blockIdx.y << 4;
    const int d   = blockIdx.z;
    __shared__ float tile[64][81];
    const float* wb = w + ((long)d * 1024 + oc0) * 640 + ic0 * 5;
    for (int i = threadIdx.x; i < 64 * 80; i += 256) {
        int oc_l = i / 80, idx = i % 80;          // idx = ic_l*5 + s
        tile[oc_l][idx] = wb[(long)oc_l * 640 + idx];
    }
    __syncthreads();
    float* wo = wt + (long)d * 5 * 128 * 1024 + oc0;
    for (int j = threadIdx.x; j < 80 * 64; j += 256) {
        int oc_l = j & 63, r = j >> 6;            // r = ic_l*5 + s
        int ic_l = r / 5, s = r - ic_l * 5;
        wo[((long)s * 128 + ic0 + ic_l) * 1024 + oc_l] = tile[oc_l][r];
    }
}

// ---------------------------------------------------------------------------
// Coalesced per-layer matrix transpose: (D, N, Kd) -> (D, Kd, N).
// 32x32 LDS tile, 33-pad. grid (N/32, Kd/32, D), block 256.
__global__ __launch_bounds__(256) void k_tp_mat_t(const float* __restrict__ in,
                                                  float* __restrict__ out,
                                                  int N, int Kd) {
    const int n0 = blockIdx.x << 5;
    const int k0 = blockIdx.y << 5;
    const int d  = blockIdx.z;
    __shared__ float t[32][33];
    const float* ib = in + ((long)d * N + n0) * Kd + k0;
    for (int i = threadIdx.x; i < 1024; i += 256) {
        int n_l = i >> 5, k_l = i & 31;
        t[n_l][k_l] = ib[(long)n_l * Kd + k_l];
    }
    __syncthreads();
    float* ob = out + ((long)d * Kd + k0) * N + n0;
    for (int j = threadIdx.x; j < 1024; j += 256) {
        int k_l = j >> 5, n_l = j & 31;
        ob[(long)k_l * N + n_l] = t[n_l][k_l];
    }
}

// ---------------------------------------------------------------------------
// Fused q/k/v conv. Output written directly in "prep" layout:
//   P[((b*T + t)*H + hh)*K + kq] = scale * (conv[b][kq*8+hh][t] + bias)
// grid: x = B*(T/64)=64, y = OC/256=4, z = 3 (0=q,1=k,2=v). block 512.
__global__ __launch_bounds__(512) void k_conv_qkv(
    const float* __restrict__ xb, const float* __restrict__ qT,
    const float* __restrict__ kT, const float* __restrict__ vT,
    const float* __restrict__ qb, const float* __restrict__ kb,
    float* __restrict__ Qp, float* __restrict__ Kp, float* __restrict__ Vp,
    int d)
{
    const int which = blockIdx.z;
    const int b  = blockIdx.x >> 4;
    const int t0 = (blockIdx.x & 15) << 6;
    const int oc0 = blockIdx.y << 8;
    __shared__ float xs[68][Kz];
    for (int i = threadIdx.x; i < 68 * (Kz / 4); i += 512) {
        int row = i >> 5, c4 = i & 31;
        int t = t0 - 4 + row;
        float4 v = make_float4(0.f, 0.f, 0.f, 0.f);
        if (t >= 0)
            v = reinterpret_cast<const float4*>(xb + ((long)b * Tz + t) * Kz)[c4];
        reinterpret_cast<float4*>(&xs[row][0])[c4] = v;
    }
    __syncthreads();

    const int ocq = threadIdx.x & 63;
    const int tg  = threadIdx.x >> 6;      // 0..7 -> rows tg*8 .. tg*8+7
    const int oc  = oc0 + ocq * 4;

    float acc[8][4];
#pragma unroll
    for (int i = 0; i < 8; ++i)
#pragma unroll
        for (int j = 0; j < 4; ++j) acc[i][j] = 0.f;

    const float* wbase = (which == 0) ? qT + (long)d * KSz * Kz * 1024
                       : (which == 1) ? kT + (long)d * KSz * Kz * 1024
                                      : vT + (long)d * Kz * 1024;

    if (which == 2) {
        // kernel-size-1 conv
        for (int icb = 0; icb < Kz; icb += 4) {
            float4 xr[8];
#pragma unroll
            for (int i = 0; i < 8; ++i)
                xr[i] = *reinterpret_cast<const float4*>(&xs[tg * 8 + 4 + i][icb]);
#pragma unroll
            for (int u = 0; u < 4; ++u) {
                float4 wv = *reinterpret_cast<const float4*>(wbase + (icb + u) * 1024 + oc);
#pragma unroll
                for (int i = 0; i < 8; ++i) {
                    float xv = (&xr[i].x)[u];
                    acc[i][0] = fmaf(xv, wv.x, acc[i][0]);
                    acc[i][1] = fmaf(xv, wv.y, acc[i][1]);
                    acc[i][2] = fmaf(xv, wv.z, acc[i][2]);
                    acc[i][3] = fmaf(xv, wv.w, acc[i][3]);
                }
            }
        }
    } else {
        for (int icb = 0; icb < Kz; icb += 4) {
            float4 xr[12];
#pragma unroll
            for (int r = 0; r < 12; ++r)
                xr[r] = *reinterpret_cast<const float4*>(&xs[tg * 8 + r][icb]);
#pragma unroll
            for (int s = 0; s < KSz; ++s) {
#pragma unroll
                for (int u = 0; u < 4; ++u) {
                    float4 wv = *reinterpret_cast<const float4*>(
                        wbase + ((long)s * Kz + icb + u) * 1024 + oc);
#pragma unroll
                    for (int i = 0; i < 8; ++i) {
                        float x1 = (&xr[i + s].x)[u];
                        acc[i][0] = fmaf(x1, wv.x, acc[i][0]);
                        acc[i][1] = fmaf(x1, wv.y, acc[i][1]);
                        acc[i][2] = fmaf(x1, wv.z, acc[i][2]);
                        acc[i][3] = fmaf(x1, wv.w, acc[i][3]);
                    }
                }
            }
        }
    }

    float bias[4] = {0.f, 0.f, 0.f, 0.f};
    float scale = 1.f;
    if (which == 0) {
#pragma unroll
        for (int j = 0; j < 4; ++j) bias[j] = qb[d * 1024 + oc + j];
        scale = SCALEf;
    } else if (which == 1) {
#pragma unroll
        for (int j = 0; j < 4; ++j) bias[j] = kb[d * 1024 + oc + j];
        scale = SCALEf;
    }
    float* outp = (which == 0) ? Qp : (which == 1) ? Kp : Vp;
#pragma unroll
    for (int i = 0; i < 8; ++i) {
        int t = t0 + tg * 8 + i;
        long rb = ((long)b * Tz + t) * Hz;
#pragma unroll
        for (int j = 0; j < 4; ++j) {
            int occ = oc + j;
            outp[(rb + (occ & 7)) * Kz + (occ >> 3)] = (acc[i][j] + bias[j]) * scale;
        }
    }
}

// ---------------------------------------------------------------------------
// Causal flash attention over 32 scrambled sequences of (1024, 128).
// grid: x = 16 (paired q-tiles qtA=bx, qtB=31-bx -> uniform 34 tiles/block),
//       y = 32 seqs. block 256. LDS 54,272 B -> 3 blocks/CU.
__global__ __launch_bounds__(256) void k_attn(
    const float* __restrict__ Qp, const float* __restrict__ Kp,
    const float* __restrict__ Vp, float* __restrict__ attb)
{
    const int seq = blockIdx.y;
    __shared__ float qs[32][132];
    __shared__ float ksm[32][132];
    __shared__ float vs[32][128];
    __shared__ float ps[32][32];

    const int tid = threadIdx.x;
    const int ty = tid >> 4;     // 0..15 -> rows 2ty, 2ty+1
    const int tx = tid & 15;     // S cols tx / tx+16; O cols 4tx / 64+4tx
    const int r0 = ty * 2, r1 = ty * 2 + 1;
    const int bb = seq >> 3, hh = seq & 7;

    for (int pass = 0; pass < 2; ++pass) {
        const int qt = pass ? (31 - (int)blockIdx.x) : (int)blockIdx.x;

        __syncthreads();   // all LDS reads of previous pass complete
        const float* qbase = Qp + ((long)seq * Tz + qt * 32) * Kz;
        for (int i = tid; i < 32 * 32; i += 256) {
            int r = i >> 5, c4 = i & 31;
            float4 v = reinterpret_cast<const float4*>(qbase + r * Kz)[c4];
            *reinterpret_cast<float4*>(&qs[r][c4 * 4]) = v;
        }
        __syncthreads();

        float m0 = -INFINITY, m1 = -INFINITY, l0 = 0.f, l1 = 0.f;
        float o0[8], o1[8];
#pragma unroll
        for (int j = 0; j < 8; ++j) { o0[j] = 0.f; o1[j] = 0.f; }

        for (int kt = 0; kt <= qt; ++kt) {
            const float* kb2 = Kp + ((long)seq * Tz + kt * 32) * Kz;
            const float* vb2 = Vp + ((long)seq * Tz + kt * 32) * Kz;
            for (int i = tid; i < 32 * 32; i += 256) {
                int r = i >> 5, c4 = i & 31;
                float4 kv = reinterpret_cast<const float4*>(kb2 + r * Kz)[c4];
                *reinterpret_cast<float4*>(&ksm[r][c4 * 4]) = kv;
                float4 vv = reinterpret_cast<const float4*>(vb2 + r * Kz)[c4];
                reinterpret_cast<float4*>(&vs[r][0])[c4] = vv;
            }
            __syncthreads();

            float s00 = 0.f, s01 = 0.f, s10 = 0.f, s11 = 0.f;
#pragma unroll 8
            for (int c = 0; c < Kz; c += 4) {
                float4 q0 = *reinterpret_cast<const float4*>(&qs[r0][c]);
                float4 q1 = *reinterpret_cast<const float4*>(&qs[r1][c]);
                float4 ka = *reinterpret_cast<const float4*>(&ksm[tx][c]);
                float4 kb = *reinterpret_cast<const float4*>(&ksm[tx + 16][c]);
                s00 = fmaf(q0.x, ka.x, s00); s00 = fmaf(q0.y, ka.y, s00);
                s00 = fmaf(q0.z, ka.z, s00); s00 = fmaf(q0.w, ka.w, s00);
                s01 = fmaf(q0.x, kb.x, s01); s01 = fmaf(q0.y, kb.y, s01);
                s01 = fmaf(q0.z, kb.z, s01); s01 = fmaf(q0.w, kb.w, s01);
                s10 = fmaf(q1.x, ka.x, s10); s10 = fmaf(q1.y, ka.y, s10);
                s10 = fmaf(q1.z, ka.z, s10); s10 = fmaf(q1.w, ka.w, s10);
                s11 = fmaf(q1.x, kb.x, s11); s11 = fmaf(q1.y, kb.y, s11);
                s11 = fmaf(q1.z, kb.z, s11); s11 = fmaf(q1.w, kb.w, s11);
            }
            const int tq0 = qt * 32 + r0;
            const int skA = kt * 32 + tx;        // col for s00/s10
            const int skB = kt * 32 + tx + 16;   // col for s01/s11
            if (skA > tq0    ) s00 = -INFINITY;
            if (skB > tq0    ) s01 = -INFINITY;
            if (skA > tq0 + 1) s10 = -INFINITY;
            if (skB > tq0 + 1) s11 = -INFINITY;

            float rm0 = fmaxf(s00, s01), rm1 = fmaxf(s10, s11);
#pragma unroll
            for (int off = 1; off < 16; off <<= 1) {
                rm0 = fmaxf(rm0, __shfl_xor(rm0, off));
                rm1 = fmaxf(rm1, __shfl_xor(rm1, off));
            }
            float nm0 = fmaxf(m0, rm0), nm1 = fmaxf(m1, rm1);
            float p00 = __expf(s00 - nm0), p01 = __expf(s01 - nm0);
            float p10 = __expf(s10 - nm1), p11 = __expf(s11 - nm1);
            float rs0 = p00 + p01, rs1 = p10 + p11;
#pragma unroll
            for (int off = 1; off < 16; off <<= 1) {
                rs0 += __shfl_xor(rs0, off);
                rs1 += __shfl_xor(rs1, off);
            }
            float f0 = __expf(m0 - nm0), f1 = __expf(m1 - nm1);
            l0 = l0 * f0 + rs0;
            l1 = l1 * f1 + rs1;
            m0 = nm0; m1 = nm1;
#pragma unroll
            for (int j = 0; j < 8; ++j) { o0[j] *= f0; o1[j] *= f1; }
            ps[r0][tx] = p00; ps[r0][tx + 16] = p01;
            ps[r1][tx] = p10; ps[r1][tx + 16] = p11;
            __syncthreads();
#pragma unroll
            for (int kb4 = 0; kb4 < 8; ++kb4) {
                float4 p0v = *reinterpret_cast<const float4*>(&ps[r0][kb4 * 4]);
                float4 p1v = *reinterpret_cast<const float4*>(&ps[r1][kb4 * 4]);
#pragma unroll
                for (int u = 0; u < 4; ++u) {
                    int kk = kb4 * 4 + u;
                    float p0 = (&p0v.x)[u], p1 = (&p1v.x)[u];
                    float4 va = *reinterpret_cast<const float4*>(&vs[kk][4 * tx]);
                    float4 vb = *reinterpret_cast<const float4*>(&vs[kk][64 + 4 * tx]);
                    o0[0] = fmaf(p0, va.x, o0[0]); o0[1] = fmaf(p0, va.y, o0[1]);
                    o0[2] = fmaf(p0, va.z, o0[2]); o0[3] = fmaf(p0, va.w, o0[3]);
                    o0[4] = fmaf(p0, vb.x, o0[4]); o0[5] = fmaf(p0, vb.y, o0[5]);
                    o0[6] = fmaf(p0, vb.z, o0[6]); o0[7] = fmaf(p0, vb.w, o0[7]);
                    o1[0] = fmaf(p1, va.x, o1[0]); o1[1] = fmaf(p1, va.y, o1[1]);
                    o1[2] = fmaf(p1, va.z, o1[2]); o1[3] = fmaf(p1, va.w, o1[3]);
                    o1[4] = fmaf(p1, vb.x, o1[4]); o1[5] = fmaf(p1, vb.y, o1[5]);
                    o1[6] = fmaf(p1, vb.z, o1[6]); o1[7] = fmaf(p1, vb.w, o1[7]);
                }
            }
            __syncthreads();
        }
        float inv0 = 1.f / l0, inv1 = 1.f / l1;
        {
            int tt = qt * 32 + r0;
            float* op = attb + ((long)bb * Tz + tt) * (Hz * Kz) + hh * Kz;
            float4 w0 = make_float4(o0[0] * inv0, o0[1] * inv0, o0[2] * inv0, o0[3] * inv0);
            float4 w1 = make_float4(o0[4] * inv0, o0[5] * inv0, o0[6] * inv0, o0[7] * inv0);
            *reinterpret_cast<float4*>(op + 4 * tx) = w0;
            *reinterpret_cast<float4*>(op + 64 + 4 * tx) = w1;
        }
        {
            int tt = qt * 32 + r1;
            float* op = attb + ((long)bb * Tz + tt) * (Hz * Kz) + hh * Kz;
            float4 w0 = make_float4(o1[0] * inv1, o1[1] * inv1, o1[2] * inv1, o1[3] * inv1);
            float4 w1 = make_float4(o1[4] * inv1, o1[5] * inv1, o1[6] * inv1, o1[7] * inv1);
            *reinterpret_cast<float4*>(op + 4 * tx) = w0;
            *reinterpret_cast<float4*>(op + 64 + 4 * tx) = w1;
        }
    }
}

// ---------------------------------------------------------------------------
// GEMM: C = A[4096][Kd] @ WT[Kd][N]. BM=BN=128, BK=32, 8x8 thread tile.
// grid: (32, N/128, S). Split-K over grid.z: each z writes a partial slab
// C + z*4096*N (no bias); if gridDim.z==1, bias(+relu) applied directly.
// If fuseA: A-stage computes relu(A[idx] + A[idx+slabA] + biasA[k]) on the fly
// (used to consume ff1's split-K partials directly, eliding the y1 buffer).
__global__ __launch_bounds__(256) void k_gemm2(
    const float* __restrict__ A, const float* __restrict__ WT,
    const float* __restrict__ bias, float* __restrict__ C,
    int N, int Kd, int relu,
    const float* __restrict__ biasA, long slabA, int fuseA)
{
    __shared__ float as[32][132];
    __shared__ float wsh[32][132];
    const int tid = threadIdx.x;
    const int m0 = blockIdx.x << 7;
    const int n0 = blockIdx.y << 7;
    const int rg = tid >> 4;    // 8-row group
    const int cg = tid & 15;    // 8-col group

    float acc[8][8];
#pragma unroll
    for (int i = 0; i < 8; ++i)
#pragma unroll
        for (int j = 0; j < 8; ++j) acc[i][j] = 0.f;

    const int ks = Kd / gridDim.z;
    const int kbeg = blockIdx.z * ks;
    const int kend = kbeg + ks;

    for (int k0 = kbeg; k0 < kend; k0 += 32) {
        // stage A transposed: as[kk][m]
#pragma unroll
        for (int c = 0; c < 4; ++c) {
            int m = c * 32 + (tid >> 3);
            int kq = (tid & 7) * 4;
            long idx = (long)(m0 + m) * Kd + k0 + kq;
            float4 v = *reinterpret_cast<const float4*>(A + idx);
            if (fuseA) {
                float4 v1 = *reinterpret_cast<const float4*>(A + idx + slabA);
                float4 bA = *reinterpret_cast<const float4*>(biasA + k0 + kq);
                v.x = fmaxf(v.x + v1.x + bA.x, 0.f);
                v.y = fmaxf(v.y + v1.y + bA.y, 0.f);
                v.z = fmaxf(v.z + v1.z + bA.z, 0.f);
                v.w = fmaxf(v.w + v1.w + bA.w, 0.f);
            }
            as[kq + 0][m] = v.x; as[kq + 1][m] = v.y;
            as[kq + 2][m] = v.z; as[kq + 3][m] = v.w;
        }
        // stage W direct: wsh[kk][n]
#pragma unroll
        for (int c = 0; c < 4; ++c) {
            int kk = c * 8 + (tid >> 5);
            int nq = (tid & 31) * 4;
            float4 w = *reinterpret_cast<const float4*>(WT + (long)(k0 + kk) * N + n0 + nq);
            *reinterpret_cast<float4*>(&wsh[kk][nq]) = w;
        }
        __syncthreads();
#pragma unroll 4
        for (int kk = 0; kk < 32; ++kk) {
            float4 a0 = *reinterpret_cast<const float4*>(&as[kk][rg * 8]);
            float4 a1 = *reinterpret_cast<const float4*>(&as[kk][rg * 8 + 4]);
            float4 w0 = *reinterpret_cast<const float4*>(&wsh[kk][cg * 8]);
            float4 w1 = *reinterpret_cast<const float4*>(&wsh[kk][cg * 8 + 4]);
            float ar[8] = {a0.x, a0.y, a0.z, a0.w, a1.x, a1.y, a1.z, a1.w};
            float wr[8] = {w0.x, w0.y, w0.z, w0.w, w1.x, w1.y, w1.z, w1.w};
#pragma unroll
            for (int i = 0; i < 8; ++i)
#pragma unroll
                for (int j = 0; j < 8; ++j)
                    acc[i][j] = fmaf(ar[i], wr[j], acc[i][j]);
        }
        __syncthreads();
    }

    if (gridDim.z == 1) {
        float4 bv0 = *reinterpret_cast<const float4*>(bias + n0 + cg * 8);
        float4 bv1 = *reinterpret_cast<const float4*>(bias + n0 + cg * 8 + 4);
        float br[8] = {bv0.x, bv0.y, bv0.z, bv0.w, bv1.x, bv1.y, bv1.z, bv1.w};
#pragma unroll
        for (int i = 0; i < 8; ++i) {
            float v[8];
#pragma unroll
            for (int j = 0; j < 8; ++j) {
                v[j] = acc[i][j] + br[j];
                if (relu) v[j] = fmaxf(v[j], 0.f);
            }
            float* cp = C + (long)(m0 + rg * 8 + i) * N + n0 + cg * 8;
            *reinterpret_cast<float4*>(cp)     = make_float4(v[0], v[1], v[2], v[3]);
            *reinterpret_cast<float4*>(cp + 4) = make_float4(v[4], v[5], v[6], v[7]);
        }
    } else {
        float* outp = C + (long)blockIdx.z * 4096 * N;
#pragma unroll
        for (int i = 0; i < 8; ++i) {
            float* cp = outp + (long)(m0 + rg * 8 + i) * N + n0 + cg * 8;
            *reinterpret_cast<float4*>(cp)     = make_float4(acc[i][0], acc[i][1], acc[i][2], acc[i][3]);
            *reinterpret_cast<float4*>(cp + 4) = make_float4(acc[i][4], acc[i][5], acc[i][6], acc[i][7]);
        }
    }
}

// ---------------------------------------------------------------------------
// x = LayerNorm( (sum_s P[s]) + gbias + x ) * s + b  (fused split-K reduce).
// If outp != nullptr (final layer): also emit mu = xn@mu_w + mu_b and
// sigma = softplus(xn@sig_w + sig_b) per row.
__global__ __launch_bounds__(256) void k_add_ln_r(
    const float* __restrict__ P, int S, const float* __restrict__ gb,
    float* __restrict__ x, const float* __restrict__ sc, const float* __restrict__ bsh,
    const float* __restrict__ muw, const float* __restrict__ mub,
    const float* __restrict__ sgw, const float* __restrict__ sgb,
    float* __restrict__ outp)
{
    const int wave = threadIdx.x >> 6, lane = threadIdx.x & 63;
    const long row = (long)blockIdx.x * 4 + wave;
    float v0 = 0.f, v1 = 0.f;
    for (int si = 0; si < S; ++si) {
        float2 p = reinterpret_cast<const float2*>(P + (long)si * 4096 * Kz + row * Kz)[lane];
        v0 += p.x; v1 += p.y;
    }
    float2 g = reinterpret_cast<const float2*>(gb)[lane];
    float* xr = x + row * Kz;
    float2 xv = reinterpret_cast<const float2*>(xr)[lane];
    v0 += g.x + xv.x; v1 += g.y + xv.y;
    float sum = v0 + v1;
#pragma unroll
    for (int off = 1; off < 64; off <<= 1) sum += __shfl_xor(sum, off);
    float mean = sum * (1.f / Kz);
    float d0 = v0 - mean, d1 = v1 - mean;
    float vv = d0 * d0 + d1 * d1;
#pragma unroll
    for (int off = 1; off < 64; off <<= 1) vv += __shfl_xor(vv, off);
    float rstd = rsqrtf(vv * (1.f / Kz) + EPSz);
    float2 sv = reinterpret_cast<const float2*>(sc)[lane];
    float2 bv = reinterpret_cast<const float2*>(bsh)[lane];
    float2 ov;
    ov.x = d0 * rstd * sv.x + bv.x;
    ov.y = d1 * rstd * sv.y + bv.y;
    reinterpret_cast<float2*>(xr)[lane] = ov;

    if (outp) {
        float2 mw = reinterpret_cast<const float2*>(muw)[lane];
        float2 sw = reinterpret_cast<const float2*>(sgw)[lane];
        float am  = ov.x * mw.x + ov.y * mw.y;
        float as2 = ov.x * sw.x + ov.y * sw.y;
#pragma unroll
        for (int off = 1; off < 64; off <<= 1) {
            am  += __shfl_xor(am, off);
            as2 += __shfl_xor(as2, off);
        }
        if (lane == 0) {
            outp[row] = am + mub[0];
            float z = as2 + sgb[0];
            outp[(long)Bz * Tz + row] = (z > 20.f) ? z : log1pf(expf(z));
        }
    }
}

// ---------------------------------------------------------------------------
extern "C" void kernel_launch(void* const* d_in, const int* in_sizes, int n_in,
                              void* d_out, int out_size, void* d_ws, size_t ws_size,
                              hipStream_t stream) {
    const float* x     = (const float*)d_in[0];
    const float* pos   = (const float*)d_in[1];
    const float* q_w   = (const float*)d_in[2];
    const float* q_b   = (const float*)d_in[3];
    const float* k_w   = (const float*)d_in[4];
    const float* k_b   = (const float*)d_in[5];
    const float* v_w   = (const float*)d_in[6];
    const float* uni_w = (const float*)d_in[7];
    const float* uni_b = (const float*)d_in[8];
    const float* ln1_s = (const float*)d_in[9];
    const float* ln1_b = (const float*)d_in[10];
    const float* ln2_s = (const float*)d_in[11];
    const float* ln2_b = (const float*)d_in[12];
    const float* ff1_w = (const float*)d_in[13];
    const float* ff1_b = (const float*)d_in[14];
    const float* ff2_w = (const float*)d_in[15];
    const float* ff2_b = (const float*)d_in[16];
    const float* mu_w  = (const float*)d_in[17];
    const float* mu_b  = (const float*)d_in[18];
    const float* sig_w = (const float*)d_in[19];
    const float* sig_b = (const float*)d_in[20];
    float* out = (float*)d_out;

    // workspace layout (floats); total 28,311,552 floats = 113.2 MB (compact)
    float* ws   = (float*)d_ws;
    float* xb   = ws;                       // 524288
    float* qT   = xb   + 524288;            // 2621440  (D,5,128,1024)
    float* kT   = qT   + 2621440;           // 2621440
    float* vT   = kT   + 2621440;           // 524288   (D,128,1024)
    float* uniT = vT   + 524288;            // 524288   (D,1024,128)
    float* f1T  = uniT + 524288;            // 262144   (D,128,512)
    float* f2T  = f1T  + 262144;            // 262144   (D,512,128)
    float* Qp   = f2T  + 262144;            // 4194304  (32,1024,128)
    float* Kp   = Qp   + 4194304;           // 4194304
    float* Vp   = Kp   + 4194304;           // 4194304
    float* attb = Vp   + 4194304;           // 4194304  attn out / ff2 partials
    float* Pp   = attb + 4194304;           // 4194304  uni/ff1 partials

    // x + pos
    k_add_pos<<<512, 256, 0, stream>>>(x, pos, xb);

    // coalesced weight transposes (inputs restored every call; redo each launch)
    k_tp_conv_t<<<dim3(16, 8, Dz), 256, 0, stream>>>(q_w, qT);
    k_tp_conv_t<<<dim3(16, 8, Dz), 256, 0, stream>>>(k_w, kT);
    k_tp_mat_t<<<dim3(32, 4, Dz), 256, 0, stream>>>(v_w,   vT,   1024, 128);
    k_tp_mat_t<<<dim3(4, 32, Dz), 256, 0, stream>>>(uni_w, uniT, 128, 1024);
    k_tp_mat_t<<<dim3(16, 4, Dz), 256, 0, stream>>>(ff1_w, f1T,  512, 128);
    k_tp_mat_t<<<dim3(4, 16, Dz), 256, 0, stream>>>(ff2_w, f2T,  128, 512);

    for (int d = 0; d < Dz; ++d) {
        const int last = (d == Dz - 1);
        // q/k causal convs + v projection, written in prep layout (t-tile 64)
        k_conv_qkv<<<dim3(64, 4, 3), 512, 0, stream>>>(
            xb, qT, kT, vT, q_b, k_b, Qp, Kp, Vp, d);
        // causal flash attention, paired q-tiles for load balance
        k_attn<<<dim3(16, 32), 256, 0, stream>>>(Qp, Kp, Vp, attb);
        // uni projection: (4096,1024)@(1024,128), split-K 8 -> Pp partials
        k_gemm2<<<dim3(32, 1, 8), 256, 0, stream>>>(
            attb, uniT + (long)d * 1024 * 128, uni_b + d * 128, Pp, 128, 1024, 0,
            nullptr, 0, 0);
        // x = LN(sum(Pp) + uni_b + x)
        k_add_ln_r<<<1024, 256, 0, stream>>>(
            Pp, 8, uni_b + d * 128, xb, ln1_s + d * 128, ln1_b + d * 128,
            nullptr, nullptr, nullptr, nullptr, nullptr);
        // ff1: (4096,128)@(128,512), split-K 2 -> Pp slabs 0,1 (raw partials)
        k_gemm2<<<dim3(32, 4, 2), 256, 0, stream>>>(
            xb, f1T + (long)d * 128 * 512, ff1_b + d * 512, Pp, 512, 128, 1,
            nullptr, 0, 0);
        // ff2: A = relu(Pp0+Pp1+ff1_b) fused in stage; split-K 8 -> attb partials
        k_gemm2<<<dim3(32, 1, 8), 256, 0, stream>>>(
            Pp, f2T + (long)d * 512 * 128, ff2_b + d * 128, attb, 128, 512, 0,
            ff1_b + d * 512, (long)4096 * 512, 1);
        // x = LN(sum(attb) + ff2_b + x); final layer also emits mu/sigma
        k_add_ln_r<<<1024, 256, 0, stream>>>(
            attb, 8, ff2_b + d * 128, xb, ln2_s + d * 128, ln2_b + d * 128,
            last ? mu_w : nullptr, last ? mu_b : nullptr,
            last ? sig_w : nullptr, last ? sig_b : nullptr,
            last ? out : nullptr);
    }
}